// Round 1
// baseline (74.348 us; speedup 1.0000x reference)
//
#include <hip/hip_runtime.h>

// Problem constants (from reference): x is (8, 3, 512, 512) fp32, DS=2, K=3.
#define NB 8
#define NC 3
#define NH 512
#define NW 512
#define HS (NH / 2)   // 256
#define WSZ (NW / 2)  // 256

// Each thread owns one (b, hs, wp) where wp indexes a PAIR of downscaled
// columns (ws = 2*wp, 2*wp+1). That makes every global access a contiguous
// float4 (16B/lane, fully coalesced): 6 loads + 6 stores per thread.
//
// Math per downscaled pixel: v[0..11] = the 2x2 block across 3 channels.
//   S(v) = sum(v*exp(v-m)) / sum(exp(v-m))          (softmax-weighted sum)
//   folded = n_y * n_x * S   (n = 2 at border row/col, else 3 — fold counts)
//   g = 0.9*sigmoid(folded) + 0.1 ;  out = x * g  (for all 12 pixels)
__global__ __launch_bounds__(256) void fused_softmax_gate(
    const float* __restrict__ x, float* __restrict__ out) {
    int idx = blockIdx.x * blockDim.x + threadIdx.x;
    int wp = idx & (WSZ / 2 - 1);        // 0..127
    int hs = (idx >> 7) & (HS - 1);      // 0..255
    int b  = idx >> 15;                  // 0..7
    if (b >= NB) return;

    const size_t plane = (size_t)NH * NW;
    const float* xb = x + (size_t)b * NC * plane;
    float*       ob = out + (size_t)b * NC * plane;

    const int h0 = hs * 2;
    const int w0 = wp * 4;  // float offset within the row (covers 2 ws pixels)

    // Load 6 float4: [channel][row-of-2x2]
    float4 v[NC][2];
#pragma unroll
    for (int c = 0; c < NC; ++c) {
#pragma unroll
        for (int i = 0; i < 2; ++i) {
            v[c][i] = *reinterpret_cast<const float4*>(
                xb + c * plane + (size_t)(h0 + i) * NW + w0);
        }
    }

    const float ny = (hs == 0 || hs == HS - 1) ? 2.0f : 3.0f;

    float g[2];
#pragma unroll
    for (int px = 0; px < 2; ++px) {  // px=0 -> (.x,.y), px=1 -> (.z,.w)
        float vv[12];
#pragma unroll
        for (int c = 0; c < NC; ++c) {
#pragma unroll
            for (int i = 0; i < 2; ++i) {
                float a0 = (px == 0) ? v[c][i].x : v[c][i].z;
                float a1 = (px == 0) ? v[c][i].y : v[c][i].w;
                vv[c * 4 + i * 2 + 0] = a0;
                vv[c * 4 + i * 2 + 1] = a1;
            }
        }
        float m = vv[0];
#pragma unroll
        for (int k = 1; k < 12; ++k) m = fmaxf(m, vv[k]);
        float se = 0.0f, sv = 0.0f;
#pragma unroll
        for (int k = 0; k < 12; ++k) {
            float e = expf(vv[k] - m);
            se += e;
            sv = fmaf(vv[k], e, sv);
        }
        float S = sv / se;
        int ws = wp * 2 + px;
        float nx = (ws == 0 || ws == WSZ - 1) ? 2.0f : 3.0f;
        float folded = ny * nx * S;
        float sig = 1.0f / (1.0f + expf(-folded));
        g[px] = fmaf(0.9f, sig, 0.1f);
    }

#pragma unroll
    for (int c = 0; c < NC; ++c) {
#pragma unroll
        for (int i = 0; i < 2; ++i) {
            float4 r;
            r.x = v[c][i].x * g[0];
            r.y = v[c][i].y * g[0];
            r.z = v[c][i].z * g[1];
            r.w = v[c][i].w * g[1];
            *reinterpret_cast<float4*>(ob + c * plane + (size_t)(h0 + i) * NW + w0) = r;
        }
    }
}

extern "C" void kernel_launch(void* const* d_in, const int* in_sizes, int n_in,
                              void* d_out, int out_size, void* d_ws, size_t ws_size,
                              hipStream_t stream) {
    const float* x = (const float*)d_in[0];
    float* out = (float*)d_out;
    // total threads = NB * HS * (WSZ/2) = 8 * 256 * 128 = 262144
    const int threads = 256;
    const int blocks = (NB * HS * (WSZ / 2)) / threads;  // 1024
    fused_softmax_gate<<<blocks, threads, 0, stream>>>(x, out);
}